// Round 4
// baseline (2815.904 us; speedup 1.0000x reference)
//
#include <hip/hip_runtime.h>
#include <cmath>

#define NB   16
#define LL   1024
#define DD   512
#define NCLS 64

// ---------------------------------------------------------------- scan helpers
// 8-lane-group sum via DPP (VALU cross-lane) instead of ds_swizzle (LDS pipe).
template<int CTRL>
__device__ __forceinline__ float dpp_add(float x) {
  int s = __builtin_amdgcn_update_dpp(0, __float_as_int(x), CTRL, 0xF, 0xF, true);
  return x + __int_as_float(s);
}
__device__ __forceinline__ float wave_red8(float y) {
  y = dpp_add<0xB1>(y);    // quad_perm xor1
  y = dpp_add<0x4E>(y);    // quad_perm xor2
  y = dpp_add<0x141>(y);   // row_half_mirror (other quad of the 8-group)
  return y;
}

// fast tanh via v_exp_f32 + v_rcp_f32; |err|~1e-7, recurrence contractive.
__device__ __forceinline__ float fast_tanh(float x) {
  float e = __expf(2.0f * x);
  return 1.0f - __fdividef(2.0f, 1.0f + e);
}

__device__ __forceinline__ float poll_ld(const float* p) {
  return __hip_atomic_load(p, __ATOMIC_RELAXED, __HIP_MEMORY_SCOPE_AGENT);
}
__device__ __forceinline__ void enc_st(float* p, float v) {
  __hip_atomic_store(p, v + 2.0f, __ATOMIC_RELAXED, __HIP_MEMORY_SCOPE_AGENT);
}
__device__ __forceinline__ void raw_st(float* p, float v) {
  __hip_atomic_store(p, v, __ATOMIC_RELAXED, __HIP_MEMORY_SCOPE_AGENT);
}
// 64-MAC dot with 4 independent accumulation chains (float4 components).
__device__ __forceinline__ void dot64(const float* w, const float4* h4, float4& a) {
  #pragma unroll
  for (int q = 0; q < 16; ++q) {
    float4 h = h4[q];
    a.x += w[4*q+0]*h.x; a.y += w[4*q+1]*h.y;
    a.z += w[4*q+2]*h.z; a.w += w[4*q+3]*h.w;
  }
}
__device__ __forceinline__ float hsum4(const float4& a) { return (a.x+a.y)+(a.z+a.w); }

// --------------------------------------------------- merged scan + embed-GEMM
// Grid = 2560 WGs x 256 thr, ONE kernel:
//   blockIdx 0..511   : persistent RNN scan (round-1 structure: WG-wide poll
//                       staging, one __syncthreads per step, M1 / M3 / M2
//                       ordering, layer-split 2x16x16, XCD map g%8==b%8).
//   blockIdx 512..2559: embed-gather + input-proj GEMM, t-major block order,
//                       writes xproj+bias-4 via AGENT atomics into Bbuf.
// Deadlock safety by CAPACITY, not dispatch order: __launch_bounds__(256,3)
// guarantees 3 WGs/CU = 768 resident slots; the 512 spinning scan WGs can
// occupy at most 512, leaving >=256 slots where gemm WGs (no dependencies)
// always stream through and retire, under ANY dispatch order.
// Bbuf slot lifecycle: poison(-3e-13) -> xproj-4 (~-4, ready iff v<-2.5)
//                      -> h1+2 (>1, ready for layer-2 iff v>1).
__global__ __launch_bounds__(256, 3) void k_scan(
    const int* __restrict__ x, const float* __restrict__ emb,
    const float* __restrict__ W_ih, const float* __restrict__ W_hh,
    const float* __restrict__ b_ih, const float* __restrict__ b_hh,
    float* __restrict__ Bbuf,   // xproj-4 -> h1+2 (in-place)
    float* __restrict__ Abuf)   // h2+2 (O2, encoded)
{
  __shared__ __align__(16) float smem[4352];   // union: gemm 17408B / scan 8704B
  const int g = blockIdx.x;
  const int tid = threadIdx.x;

  if (g >= 512) {
    // =================== embed-gather + proj GEMM path ======================
    // C[m][n] = bias[n] - 4 + sum_k emb[x[m]][k] * Wih0[n][k]; m = b*LL + t.
    float* As = smem;           // [32][68] (k-major, +4 pad)
    float* Ws = smem + 2176;    // [32][68]
    const int gb = g - 512;                  // 0..2047
    const int n0 = (gb & 7) * 64;
    const int mm = gb >> 3;                  // 0..255
    // t-major: first 128 blocks cover t in [0,64) for ALL batches.
    const int m0 = (mm & 15) * LL + (mm >> 4) * 64;
    const int tm = tid & 15, tn = tid >> 4;
    float acc[4][4] = {};

    const int f0 = tid * 2, f1 = tid * 2 + 1;
    const int r0 = f0 >> 3, q0 = f0 & 7;
    const int r1 = f1 >> 3, q1 = f1 & 7;
    const long arow0 = (long)x[m0 + r0] * DD;
    const long arow1 = (long)x[m0 + r1] * DD;
    const long wrow0 = (long)(n0 + r0) * DD;
    const long wrow1 = (long)(n0 + r1) * DD;

    for (int k0 = 0; k0 < DD; k0 += 32) {
      float4 va = *(const float4*)(emb + arow0 + k0 + q0 * 4);
      float4 vb = *(const float4*)(emb + arow1 + k0 + q1 * 4);
      float4 wa = *(const float4*)(W_ih + wrow0 + k0 + q0 * 4);
      float4 wb = *(const float4*)(W_ih + wrow1 + k0 + q1 * 4);
      __syncthreads();
      As[(q0*4+0)*68+r0]=va.x; As[(q0*4+1)*68+r0]=va.y;
      As[(q0*4+2)*68+r0]=va.z; As[(q0*4+3)*68+r0]=va.w;
      As[(q1*4+0)*68+r1]=vb.x; As[(q1*4+1)*68+r1]=vb.y;
      As[(q1*4+2)*68+r1]=vb.z; As[(q1*4+3)*68+r1]=vb.w;
      Ws[(q0*4+0)*68+r0]=wa.x; Ws[(q0*4+1)*68+r0]=wa.y;
      Ws[(q0*4+2)*68+r0]=wa.z; Ws[(q0*4+3)*68+r0]=wa.w;
      Ws[(q1*4+0)*68+r1]=wb.x; Ws[(q1*4+1)*68+r1]=wb.y;
      Ws[(q1*4+2)*68+r1]=wb.z; Ws[(q1*4+3)*68+r1]=wb.w;
      __syncthreads();
      #pragma unroll
      for (int kk = 0; kk < 32; ++kk) {
        float4 a = *(const float4*)&As[kk*68 + tm*4];
        float4 w = *(const float4*)&Ws[kk*68 + tn*4];
        acc[0][0]+=a.x*w.x; acc[0][1]+=a.x*w.y; acc[0][2]+=a.x*w.z; acc[0][3]+=a.x*w.w;
        acc[1][0]+=a.y*w.x; acc[1][1]+=a.y*w.y; acc[1][2]+=a.y*w.z; acc[1][3]+=a.y*w.w;
        acc[2][0]+=a.z*w.x; acc[2][1]+=a.z*w.y; acc[2][2]+=a.z*w.z; acc[2][3]+=a.z*w.w;
        acc[3][0]+=a.w*w.x; acc[3][1]+=a.w*w.y; acc[3][2]+=a.w*w.z; acc[3][3]+=a.w*w.w;
      }
    }
    float bj[4];
    #pragma unroll
    for (int jq = 0; jq < 4; ++jq)
      bj[jq] = b_ih[n0 + tn*4 + jq] + b_hh[n0 + tn*4 + jq] - 4.0f;
    #pragma unroll
    for (int i = 0; i < 4; ++i) {
      const int m = m0 + tm*4 + i;
      float* base = Bbuf + (long)m * DD + n0 + tn*4;
      #pragma unroll
      for (int jq = 0; jq < 4; ++jq)
        raw_st(base + jq, acc[i][jq] + bj[jq]);   // agent-visible (cross-XCD)
    }
    return;
  }

  // ========================== persistent scan path ==========================
  const int lay = g >> 8;          // 0: h1 chain, 1: h2 chain
  const int b = g & 15;            // batch (g%8 == b%8 both halves)
  const int j = (g & 255) >> 4;    // WG index within (layer,batch) [0,16)
  const int rl  = tid >> 3;        // row_local [0,32)
  const int part = tid & 7;        // k-part [0,8), 64 elems each
  const int row = j * 32 + rl;     // global hidden row
  const bool leader = (part == 0);

  float* hSa = smem;               // [2][544] stage A (h1 for lay0; h2 for lay1)
  float* hSb = smem + 1088;        // [2][544] stage B (h1 for lay1's M2)

  float* Bb = Bbuf + (long)b * LL * DD;
  float* Ab = Abuf + (long)b * LL * DD;

  const int i0 = tid, i1 = tid + 256;
  const int d0 = (i0 >> 6) * 68 + (i0 & 63);
  const int d1 = (i1 >> 6) * 68 + (i1 & 63);

  if (lay == 0) {
    // ------------ layer 1: h1(t) = tanh(xproj(t) + Whh1 . h1(t-1)) ----------
    float w1[64];
    {
      const float* p1 = W_hh + (long)row * DD + part * 64;
      #pragma unroll
      for (int q = 0; q < 64; ++q) w1[q] = p1[q];
    }
    #pragma unroll
    for (int q = 0; q < 64; ++q) asm volatile("" : "+v"(w1[q]));  // pin in VGPRs

    float xpv = 0.f, xnext = 0.f;
    if (leader) {
      float v = poll_ld(Bb + row);                 // xproj(0): ready iff < -2.5
      while (v > -2.5f) v = poll_ld(Bb + row);
      xpv = v + 4.0f;
      xnext = poll_ld(Bb + DD + row);              // racing prefetch of xproj(1)
      enc_st(Bb + row, fast_tanh(xpv));            // h1(0)
    }
    for (int t = 1; t < LL; ++t) {
      const int bufi = t & 1;
      if (leader) {
        float v = xnext;                           // usually already ready
        while (v > -2.5f) v = poll_ld(Bb + (long)t * DD + row);
        xpv = v + 4.0f;
        if (t + 1 < LL) xnext = poll_ld(Bb + (long)(t + 1) * DD + row);
      }
      // poll h1(t-1) (xproj-4 and poison both read as not-ready)
      const float* s1 = Bb + (long)(t - 1) * DD;
      float v0 = poll_ld(s1 + i0), v1 = poll_ld(s1 + i1);
      while (fminf(v0, v1) <= 1.0f) { v0 = poll_ld(s1 + i0); v1 = poll_ld(s1 + i1); }
      hSa[bufi*544 + d0] = v0 - 2.0f; hSa[bufi*544 + d1] = v1 - 2.0f;
      __syncthreads();
      float4 a = {0.f, 0.f, 0.f, 0.f};
      dot64(w1, (const float4*)(hSa + bufi*544 + part*68), a);
      float y = wave_red8(hsum4(a));
      if (leader) enc_st(Bb + (long)t * DD + row, fast_tanh(xpv + y));
    }
  } else {
    // ------ layer 2: h2(t) = tanh(Wih2.h1(t) + bias2 + Whh2.h2(t-1)) --------
    float w2[64], w3[64];
    {
      const float* p2 = W_ih + (long)DD * DD + (long)row * DD + part * 64;
      const float* p3 = W_hh + (long)DD * DD + (long)row * DD + part * 64;
      #pragma unroll
      for (int q = 0; q < 64; ++q) { w2[q] = p2[q]; w3[q] = p3[q]; }
    }
    #pragma unroll
    for (int q = 0; q < 64; ++q) {
      asm volatile("" : "+v"(w2[q]));
      asm volatile("" : "+v"(w3[q]));
    }
    const float bias2 = b_ih[DD + row] + b_hh[DD + row];

    // prologue: xin2(0) = Wih2 . h1(0) + bias2
    float xin2;
    {
      const float* s1 = Bb;
      float v0 = poll_ld(s1 + i0), v1 = poll_ld(s1 + i1);
      while (fminf(v0, v1) <= 1.0f) { v0 = poll_ld(s1 + i0); v1 = poll_ld(s1 + i1); }
      hSb[544 + d0] = v0 - 2.0f; hSb[544 + d1] = v1 - 2.0f;
      __syncthreads();
      float4 a = {0.f, 0.f, 0.f, 0.f};
      dot64(w2, (const float4*)(hSb + 544 + part*68), a);
      xin2 = wave_red8(hsum4(a)) + bias2;
    }
    // iter t: store h2(t) (using xin2(t)), then compute xin2(t+1) from h1(t+1)
    // — M2 sits between the h2 store and the next poll, hiding store->poll.
    for (int t = 0; t < LL; ++t) {
      const int bufi = t & 1;
      const bool st2 = (t >= 1);        // h2(t-1) exists
      const bool st1 = (t + 1 < LL);    // need h1(t+1)
      {
        const float* s2 = Ab + (long)(t - 1) * DD;
        const float* s1 = Bb + (long)(t + 1) * DD;
        float u0 = 3.f, u1 = 3.f, v0 = 3.f, v1 = 3.f;
        if (st2) { u0 = poll_ld(s2 + i0); u1 = poll_ld(s2 + i1); }
        if (st1) { v0 = poll_ld(s1 + i0); v1 = poll_ld(s1 + i1); }
        while (fminf(fminf(u0, u1), fminf(v0, v1)) <= 1.0f) {
          if (st2) { u0 = poll_ld(s2 + i0); u1 = poll_ld(s2 + i1); }
          if (st1) { v0 = poll_ld(s1 + i0); v1 = poll_ld(s1 + i1); }
        }
        if (st2) { hSa[bufi*544 + d0] = u0 - 2.0f; hSa[bufi*544 + d1] = u1 - 2.0f; }
        if (st1) { hSb[bufi*544 + d0] = v0 - 2.0f; hSb[bufi*544 + d1] = v1 - 2.0f; }
      }
      __syncthreads();
      // M3: h2(t) = tanh(xin2(t) + Whh2 . h2(t-1))
      float y3 = 0.f;
      if (st2) {
        float4 a = {0.f, 0.f, 0.f, 0.f};
        dot64(w3, (const float4*)(hSa + bufi*544 + part*68), a);
        y3 = hsum4(a);
      }
      y3 = wave_red8(y3);
      if (leader) enc_st(Ab + (long)t * DD + row, fast_tanh(xin2 + y3));
      // M2: xin2(t+1) = Wih2 . h1(t+1) + bias2 (off the h2 critical hop)
      if (st1) {
        float4 a = {0.f, 0.f, 0.f, 0.f};
        dot64(w2, (const float4*)(hSb + bufi*544 + part*68), a);
        xin2 = wave_red8(hsum4(a)) + bias2;
      }
    }
  }
}

// ------------------------------------------- attention row @ eos + decode head
// O2 is stored ENCODED (h+2). Decode: q explicitly; scores via qsum trick;
// att_z via sum(p)=1 -> subtract 2 at the end.
__global__ __launch_bounds__(256) void k_attn(
    const float* __restrict__ O2, const int* __restrict__ eos,
    const float* __restrict__ Wc, const float* __restrict__ bc,
    const float* __restrict__ Wd, const float* __restrict__ bd,
    float* __restrict__ out)
{
  const int b = blockIdx.x;
  const int tid = threadIdx.x;
  const int te = eos[b];
  __shared__ __align__(16) float q[DD];
  __shared__ float ps[LL];
  __shared__ float red[256];
  __shared__ __align__(16) float din[2 * DD];
  __shared__ __align__(16) float dvec[DD];
  const float* Ob = O2 + (long)b * LL * DD;
  const float4* Ob4 = (const float4*)Ob;

  float qpart = 0.f;
  for (int i = tid; i < DD; i += 256) {
    float v = Ob[(long)te * DD + i] - 2.0f;   // decode
    q[i] = v; qpart += v;
  }
  red[tid] = qpart; __syncthreads();
  for (int off = 128; off > 0; off >>= 1) {
    if (tid < off) red[tid] += red[tid + off];
    __syncthreads();
  }
  const float qsum = red[0];
  __syncthreads();
  const float4* q4 = (const float4*)q;

  // masked scores: raw dot(o_enc, q) - 2*qsum == dot(o, q)
  for (int ss = tid; ss < LL; ss += 256) {
    float sc = -1.0e9f;
    if (ss < te) {
      float4 acc = {0.f, 0.f, 0.f, 0.f};
      for (int kq = 0; kq < 128; ++kq) {
        float4 o = Ob4[ss * 128 + kq];
        float4 qq = q4[kq];
        acc.x += o.x*qq.x; acc.y += o.y*qq.y; acc.z += o.z*qq.z; acc.w += o.w*qq.w;
      }
      sc = acc.x + acc.y + acc.z + acc.w - 2.0f * qsum;
    }
    ps[ss] = sc;
  }
  __syncthreads();
  float m = -3.0e38f;
  for (int ss = tid; ss < LL; ss += 256) m = fmaxf(m, ps[ss]);
  red[tid] = m; __syncthreads();
  for (int off = 128; off > 0; off >>= 1) {
    if (tid < off) red[tid] = fmaxf(red[tid], red[tid + off]);
    __syncthreads();
  }
  m = red[0]; __syncthreads();
  float lsum = 0.f;
  for (int ss = tid; ss < LL; ss += 256) {
    float e = expf(ps[ss] - m);
    ps[ss] = e; lsum += e;
  }
  __syncthreads();
  red[tid] = lsum; __syncthreads();
  for (int off = 128; off > 0; off >>= 1) {
    if (tid < off) red[tid] += red[tid + off];
    __syncthreads();
  }
  const float inv = 1.0f / red[0];
  __syncthreads();
  for (int ss = tid; ss < LL; ss += 256) ps[ss] *= inv;
  __syncthreads();

  // att_z (encoded: sum p*o_enc - 2 since sum p = 1), z-copy (already decoded)
  if (tid < 128) {
    float4 acc = {0.f, 0.f, 0.f, 0.f};
    for (int ss = 0; ss < LL; ++ss) {
      float p = ps[ss];
      if (p != 0.0f) {
        float4 o = Ob4[ss * 128 + tid];
        acc.x += p*o.x; acc.y += p*o.y; acc.z += p*o.z; acc.w += p*o.w;
      }
    }
    acc.x -= 2.0f; acc.y -= 2.0f; acc.z -= 2.0f; acc.w -= 2.0f;
    ((float4*)din)[tid] = acc;
  } else {
    const int c = tid - 128;
    ((float4*)din)[128 + c] = q4[c];
  }
  __syncthreads();

  const float4* din4 = (const float4*)din;
  for (int jj = tid; jj < DD; jj += 256) {
    const float4* wrow = (const float4*)(Wc + (long)jj * 2 * DD);
    float4 acc = {0.f, 0.f, 0.f, 0.f};
    for (int iq = 0; iq < 256; ++iq) {
      float4 w = wrow[iq]; float4 d = din4[iq];
      acc.x += w.x*d.x; acc.y += w.y*d.y; acc.z += w.z*d.z; acc.w += w.w*d.w;
    }
    dvec[jj] = bc[jj] + acc.x + acc.y + acc.z + acc.w;
  }
  __syncthreads();

  if (tid < NCLS) {
    const float4* wrow = (const float4*)(Wd + (long)tid * DD);
    const float4* dv4 = (const float4*)dvec;
    float4 acc = {0.f, 0.f, 0.f, 0.f};
    for (int iq = 0; iq < 128; ++iq) {
      float4 w = wrow[iq]; float4 d = dv4[iq];
      acc.x += w.x*d.x; acc.y += w.y*d.y; acc.z += w.z*d.z; acc.w += w.w*d.w;
    }
    out[b * NCLS + tid] = bd[tid] + acc.x + acc.y + acc.z + acc.w;
  }
}

extern "C" void kernel_launch(void* const* d_in, const int* in_sizes, int n_in,
                              void* d_out, int out_size, void* d_ws, size_t ws_size,
                              hipStream_t stream)
{
  const int*   x    = (const int*)  d_in[0];
  const int*   eos  = (const int*)  d_in[1];
  const float* emb  = (const float*)d_in[2];
  const float* W_ih = (const float*)d_in[3];
  const float* W_hh = (const float*)d_in[4];
  const float* b_ih = (const float*)d_in[5];
  const float* b_hh = (const float*)d_in[6];
  const float* Wc   = (const float*)d_in[7];
  const float* bc   = (const float*)d_in[8];
  const float* Wd   = (const float*)d_in[9];
  const float* bd   = (const float*)d_in[10];
  float* out = (float*)d_out;

  // workspace: Abuf (h2+2) | Bbuf (xproj-4 -> h1+2).
  // Poison 0xAA = -3e-13: fails both ready tests (< -2.5 and > 1).
  float* Abuf = (float*)d_ws;
  float* Bbuf = Abuf + (size_t)NB * LL * DD;

  k_scan<<<2560, 256, 0, stream>>>(x, emb, W_ih, W_hh, b_ih, b_hh, Bbuf, Abuf);
  k_attn<<<NB, 256, 0, stream>>>(Abuf, eos, Wc, bc, Wd, bd, out);
}

// Round 5
// 2183.162 us; speedup vs baseline: 1.2898x; 1.2898x over previous
//
#include <hip/hip_runtime.h>
#include <cmath>

#define NB   16
#define LL   1024
#define DD   512
#define NCLS 64

// ---------------------------------------------- fused embed-gather + proj GEMM
// C[m][n] = b1[n] + b2[n] + sum_k emb[x[m]][k] * W[n][k]   (M=16384, N=K=512)
__global__ __launch_bounds__(256) void k_gemm_embed(
    const int* __restrict__ x, const float* __restrict__ emb,
    const float* __restrict__ W, const float* __restrict__ b1,
    const float* __restrict__ b2, float* __restrict__ C)
{
  __shared__ __align__(16) float As[32][68];  // [k][m], +4 pad
  __shared__ __align__(16) float Ws[32][68];  // [k][n]
  const int tid = threadIdx.x;
  const int n0 = (blockIdx.x & 7) * 64;
  const int m0 = (blockIdx.x >> 3) * 64;
  const int tm = tid & 15, tn = tid >> 4;
  float acc[4][4] = {};

  const int f0 = tid * 2, f1 = tid * 2 + 1;
  const int r0 = f0 >> 3, q0 = f0 & 7;
  const int r1 = f1 >> 3, q1 = f1 & 7;
  const long arow0 = (long)x[m0 + r0] * DD;
  const long arow1 = (long)x[m0 + r1] * DD;
  const long wrow0 = (long)(n0 + r0) * DD;
  const long wrow1 = (long)(n0 + r1) * DD;

  for (int k0 = 0; k0 < DD; k0 += 32) {
    float4 va = *(const float4*)(emb + arow0 + k0 + q0 * 4);
    float4 vb = *(const float4*)(emb + arow1 + k0 + q1 * 4);
    float4 wa = *(const float4*)(W + wrow0 + k0 + q0 * 4);
    float4 wb = *(const float4*)(W + wrow1 + k0 + q1 * 4);
    __syncthreads();
    As[q0*4+0][r0]=va.x; As[q0*4+1][r0]=va.y; As[q0*4+2][r0]=va.z; As[q0*4+3][r0]=va.w;
    As[q1*4+0][r1]=vb.x; As[q1*4+1][r1]=vb.y; As[q1*4+2][r1]=vb.z; As[q1*4+3][r1]=vb.w;
    Ws[q0*4+0][r0]=wa.x; Ws[q0*4+1][r0]=wa.y; Ws[q0*4+2][r0]=wa.z; Ws[q0*4+3][r0]=wa.w;
    Ws[q1*4+0][r1]=wb.x; Ws[q1*4+1][r1]=wb.y; Ws[q1*4+2][r1]=wb.z; Ws[q1*4+3][r1]=wb.w;
    __syncthreads();
    #pragma unroll
    for (int kk = 0; kk < 32; ++kk) {
      float4 a = *(const float4*)&As[kk][tm * 4];
      float4 w = *(const float4*)&Ws[kk][tn * 4];
      acc[0][0]+=a.x*w.x; acc[0][1]+=a.x*w.y; acc[0][2]+=a.x*w.z; acc[0][3]+=a.x*w.w;
      acc[1][0]+=a.y*w.x; acc[1][1]+=a.y*w.y; acc[1][2]+=a.y*w.z; acc[1][3]+=a.y*w.w;
      acc[2][0]+=a.z*w.x; acc[2][1]+=a.z*w.y; acc[2][2]+=a.z*w.z; acc[2][3]+=a.z*w.w;
      acc[3][0]+=a.w*w.x; acc[3][1]+=a.w*w.y; acc[3][2]+=a.w*w.z; acc[3][3]+=a.w*w.w;
    }
  }
  float bj[4];
  #pragma unroll
  for (int j = 0; j < 4; ++j)
    bj[j] = b1[n0 + tn * 4 + j] + b2[n0 + tn * 4 + j];
  #pragma unroll
  for (int i = 0; i < 4; ++i) {
    const int m = m0 + tm * 4 + i;
    float4 o = { acc[i][0]+bj[0], acc[i][1]+bj[1], acc[i][2]+bj[2], acc[i][3]+bj[3] };
    *(float4*)(C + (long)m * DD + n0 + tn * 4) = o;
  }
}

// ---------------------------------------------------------------- scan helpers
// 8-lane-group sum via DPP (VALU cross-lane) instead of ds_swizzle (LDS pipe).
template<int CTRL>
__device__ __forceinline__ float dpp_add(float x) {
  int s = __builtin_amdgcn_update_dpp(0, __float_as_int(x), CTRL, 0xF, 0xF, true);
  return x + __int_as_float(s);
}
__device__ __forceinline__ float wave_red8(float y) {
  y = dpp_add<0xB1>(y);    // quad_perm xor1
  y = dpp_add<0x4E>(y);    // quad_perm xor2
  y = dpp_add<0x141>(y);   // row_half_mirror (other quad of the 8-group)
  return y;
}

// fast tanh via v_exp_f32 + v_rcp_f32; |err|~1e-7, recurrence contractive.
__device__ __forceinline__ float fast_tanh(float x) {
  float e = __expf(2.0f * x);
  return 1.0f - __fdividef(2.0f, 1.0f + e);
}

__device__ __forceinline__ float poll_ld(const float* p) {
  return __hip_atomic_load(p, __ATOMIC_RELAXED, __HIP_MEMORY_SCOPE_AGENT);
}
__device__ __forceinline__ void enc_st(float* p, float v) {
  __hip_atomic_store(p, v + 2.0f, __ATOMIC_RELAXED, __HIP_MEMORY_SCOPE_AGENT);
}
// 64-MAC dot with 4 independent accumulation chains (float4 components):
// dep chain 64x~4cy (~256cy) -> 16x4cy (~70cy) + 12cy hsum. On-chain win.
__device__ __forceinline__ void dot64(const float* w, const float4* h4, float4& a) {
  #pragma unroll
  for (int q = 0; q < 16; ++q) {
    float4 h = h4[q];
    a.x += w[4*q+0]*h.x; a.y += w[4*q+1]*h.y;
    a.z += w[4*q+2]*h.z; a.w += w[4*q+3]*h.w;
  }
}
__device__ __forceinline__ float hsum4(const float4& a) { return (a.x+a.y)+(a.z+a.w); }

// ------------------------------------------------- persistent 2-layer RNN scan
// ROUND-1 VERIFIED STRUCTURE (2186us total) + dot64 4-chain accumulators.
// 512 WGs = 2 layers x 16 batches x 16 WGs (2 WGs/CU).
// XCD locality: g%8 == b%8 for BOTH halves (256%8==0, 16j%8==0).
// Layer-1 WGs run only the h1 recurrence; layer-2 WGs run the h2 recurrence
// with the Wih2.h1 dot pipelined one step ahead (M2 after the h2 store).
__global__ __launch_bounds__(256, 2) void k_scan(
    const float* __restrict__ W_ih, const float* __restrict__ W_hh,
    const float* __restrict__ b_ih, const float* __restrict__ b_hh,
    float* __restrict__ Bbuf,   // in: xproj layer1 -> h1+2 (in-place, encoded)
    float* __restrict__ Abuf)   // h2+2 (O2, encoded)
{
  const int g = blockIdx.x;
  const int lay = g >> 8;          // 0: h1 chain, 1: h2 chain
  const int b = g & 15;            // batch
  const int j = (g & 255) >> 4;    // WG index within (layer,batch) [0,16)
  const int tid = threadIdx.x;
  const int part = tid & 7;        // k-part [0,8), 64 elems each
  const int rl  = tid >> 3;        // row_local [0,32)
  const int row = j * 32 + rl;     // global hidden row
  const bool leader = (part == 0);

  __shared__ __align__(16) float hS[2][8 * 68];  // recurrence-state stage, dbuf
  __shared__ __align__(16) float hT[2][8 * 68];  // h1 stage for layer-2's M2

  float* Bb = Bbuf + (long)b * LL * DD;
  float* Ab = Abuf + (long)b * LL * DD;

  const int i0 = tid, i1 = tid + 256;
  const int d0 = (i0 >> 6) * 68 + (i0 & 63);
  const int d1 = (i1 >> 6) * 68 + (i1 & 63);

  if (lay == 0) {
    // ------------ layer 1: h1(t) = tanh(xproj(t) + Whh1 . h1(t-1)) ----------
    float w1[64];
    {
      const float* p1 = W_hh + (long)row * DD + part * 64;
      #pragma unroll
      for (int q = 0; q < 64; ++q) w1[q] = p1[q];
    }
    #pragma unroll
    for (int q = 0; q < 64; ++q) asm volatile("" : "+v"(w1[q]));  // pin in VGPRs

    float xpv = 0.f, xnext = 0.f;
    if (leader) {
      xpv   = Bb[row];            // xproj(0)  (gemm completed: plain loads ok)
      xnext = Bb[DD + row];       // prefetch xproj(1) a full step ahead
      enc_st(Bb + row, fast_tanh(xpv));   // h1(0)
    }
    for (int t = 1; t < LL; ++t) {
      const int bufi = t & 1;
      xpv = xnext;
      if (leader && (t + 1 < LL)) xnext = Bb[(long)(t + 1) * DD + row];
      // poll h1(t-1)
      const float* s1 = Bb + (long)(t - 1) * DD;
      float v0 = poll_ld(s1 + i0), v1 = poll_ld(s1 + i1);
      while (fminf(v0, v1) <= 1.0f) { v0 = poll_ld(s1 + i0); v1 = poll_ld(s1 + i1); }
      hS[bufi][d0] = v0 - 2.0f; hS[bufi][d1] = v1 - 2.0f;
      __syncthreads();
      float4 a = {0.f, 0.f, 0.f, 0.f};
      dot64(w1, (const float4*)&hS[bufi][part * 68], a);
      float y = wave_red8(hsum4(a));
      if (leader) enc_st(Bb + (long)t * DD + row, fast_tanh(xpv + y));
    }
  } else {
    // ------ layer 2: h2(t) = tanh(Wih2.h1(t) + bias2 + Whh2.h2(t-1)) --------
    float w2[64], w3[64];
    {
      const float* p2 = W_ih + (long)DD * DD + (long)row * DD + part * 64;
      const float* p3 = W_hh + (long)DD * DD + (long)row * DD + part * 64;
      #pragma unroll
      for (int q = 0; q < 64; ++q) { w2[q] = p2[q]; w3[q] = p3[q]; }
    }
    #pragma unroll
    for (int q = 0; q < 64; ++q) {
      asm volatile("" : "+v"(w2[q]));
      asm volatile("" : "+v"(w3[q]));
    }
    const float bias2 = b_ih[DD + row] + b_hh[DD + row];

    // prologue: xin2(0) = Wih2 . h1(0) + bias2
    float xin2;
    {
      const float* s1 = Bb;   // h1(0), encoded (xproj < 1 until overwritten)
      float v0 = poll_ld(s1 + i0), v1 = poll_ld(s1 + i1);
      while (fminf(v0, v1) <= 1.0f) { v0 = poll_ld(s1 + i0); v1 = poll_ld(s1 + i1); }
      hT[1][d0] = v0 - 2.0f; hT[1][d1] = v1 - 2.0f;
      __syncthreads();
      float4 a = {0.f, 0.f, 0.f, 0.f};
      dot64(w2, (const float4*)&hT[1][part * 68], a);
      xin2 = wave_red8(hsum4(a)) + bias2;
    }
    // iter t: store h2(t) (using xin2(t)), then compute xin2(t+1) from h1(t+1)
    // — M2 sits between the h2 store and the next poll, hiding store->poll.
    for (int t = 0; t < LL; ++t) {
      const int bufi = t & 1;
      const bool st2 = (t >= 1);        // h2(t-1) exists
      const bool st1 = (t + 1 < LL);    // need h1(t+1)
      {
        const float* s2 = Ab + (long)(t - 1) * DD;
        const float* s1 = Bb + (long)(t + 1) * DD;
        float u0 = 3.f, u1 = 3.f, v0 = 3.f, v1 = 3.f;
        if (st2) { u0 = poll_ld(s2 + i0); u1 = poll_ld(s2 + i1); }
        if (st1) { v0 = poll_ld(s1 + i0); v1 = poll_ld(s1 + i1); }
        while (fminf(fminf(u0, u1), fminf(v0, v1)) <= 1.0f) {
          if (st2) { u0 = poll_ld(s2 + i0); u1 = poll_ld(s2 + i1); }
          if (st1) { v0 = poll_ld(s1 + i0); v1 = poll_ld(s1 + i1); }
        }
        if (st2) { hS[bufi][d0] = u0 - 2.0f; hS[bufi][d1] = u1 - 2.0f; }
        if (st1) { hT[bufi][d0] = v0 - 2.0f; hT[bufi][d1] = v1 - 2.0f; }
      }
      __syncthreads();
      // M3: h2(t) = tanh(xin2(t) + Whh2 . h2(t-1))
      float y3 = 0.f;
      if (st2) {
        float4 a = {0.f, 0.f, 0.f, 0.f};
        dot64(w3, (const float4*)&hS[bufi][part * 68], a);
        y3 = hsum4(a);
      }
      y3 = wave_red8(y3);
      if (leader) enc_st(Ab + (long)t * DD + row, fast_tanh(xin2 + y3));
      // M2: xin2(t+1) = Wih2 . h1(t+1) + bias2 (off the h2 critical hop)
      if (st1) {
        float4 a = {0.f, 0.f, 0.f, 0.f};
        dot64(w2, (const float4*)&hT[bufi][part * 68], a);
        xin2 = wave_red8(hsum4(a)) + bias2;
      }
    }
  }
}

// ------------------------------------------- attention row @ eos + decode head
// O2 is stored ENCODED (h+2). Decode: q explicitly; scores via qsum trick;
// att_z via sum(p)=1 -> subtract 2 at the end.
__global__ __launch_bounds__(256) void k_attn(
    const float* __restrict__ O2, const int* __restrict__ eos,
    const float* __restrict__ Wc, const float* __restrict__ bc,
    const float* __restrict__ Wd, const float* __restrict__ bd,
    float* __restrict__ out)
{
  const int b = blockIdx.x;
  const int tid = threadIdx.x;
  const int te = eos[b];
  __shared__ __align__(16) float q[DD];
  __shared__ float ps[LL];
  __shared__ float red[256];
  __shared__ __align__(16) float din[2 * DD];
  __shared__ __align__(16) float dvec[DD];
  const float* Ob = O2 + (long)b * LL * DD;
  const float4* Ob4 = (const float4*)Ob;

  float qpart = 0.f;
  for (int i = tid; i < DD; i += 256) {
    float v = Ob[(long)te * DD + i] - 2.0f;   // decode
    q[i] = v; qpart += v;
  }
  red[tid] = qpart; __syncthreads();
  for (int off = 128; off > 0; off >>= 1) {
    if (tid < off) red[tid] += red[tid + off];
    __syncthreads();
  }
  const float qsum = red[0];
  __syncthreads();
  const float4* q4 = (const float4*)q;

  // masked scores: raw dot(o_enc, q) - 2*qsum == dot(o, q)
  for (int ss = tid; ss < LL; ss += 256) {
    float sc = -1.0e9f;
    if (ss < te) {
      float4 acc = {0.f, 0.f, 0.f, 0.f};
      for (int kq = 0; kq < 128; ++kq) {
        float4 o = Ob4[ss * 128 + kq];
        float4 qq = q4[kq];
        acc.x += o.x*qq.x; acc.y += o.y*qq.y; acc.z += o.z*qq.z; acc.w += o.w*qq.w;
      }
      sc = acc.x + acc.y + acc.z + acc.w - 2.0f * qsum;
    }
    ps[ss] = sc;
  }
  __syncthreads();
  float m = -3.0e38f;
  for (int ss = tid; ss < LL; ss += 256) m = fmaxf(m, ps[ss]);
  red[tid] = m; __syncthreads();
  for (int off = 128; off > 0; off >>= 1) {
    if (tid < off) red[tid] = fmaxf(red[tid], red[tid + off]);
    __syncthreads();
  }
  m = red[0]; __syncthreads();
  float lsum = 0.f;
  for (int ss = tid; ss < LL; ss += 256) {
    float e = expf(ps[ss] - m);
    ps[ss] = e; lsum += e;
  }
  __syncthreads();
  red[tid] = lsum; __syncthreads();
  for (int off = 128; off > 0; off >>= 1) {
    if (tid < off) red[tid] += red[tid + off];
    __syncthreads();
  }
  const float inv = 1.0f / red[0];
  __syncthreads();
  for (int ss = tid; ss < LL; ss += 256) ps[ss] *= inv;
  __syncthreads();

  // att_z (encoded: sum p*o_enc - 2 since sum p = 1), z-copy (already decoded)
  if (tid < 128) {
    float4 acc = {0.f, 0.f, 0.f, 0.f};
    for (int ss = 0; ss < LL; ++ss) {
      float p = ps[ss];
      if (p != 0.0f) {
        float4 o = Ob4[ss * 128 + tid];
        acc.x += p*o.x; acc.y += p*o.y; acc.z += p*o.z; acc.w += p*o.w;
      }
    }
    acc.x -= 2.0f; acc.y -= 2.0f; acc.z -= 2.0f; acc.w -= 2.0f;
    ((float4*)din)[tid] = acc;
  } else {
    const int c = tid - 128;
    ((float4*)din)[128 + c] = q4[c];
  }
  __syncthreads();

  const float4* din4 = (const float4*)din;
  for (int jj = tid; jj < DD; jj += 256) {
    const float4* wrow = (const float4*)(Wc + (long)jj * 2 * DD);
    float4 acc = {0.f, 0.f, 0.f, 0.f};
    for (int iq = 0; iq < 256; ++iq) {
      float4 w = wrow[iq]; float4 d = din4[iq];
      acc.x += w.x*d.x; acc.y += w.y*d.y; acc.z += w.z*d.z; acc.w += w.w*d.w;
    }
    dvec[jj] = bc[jj] + acc.x + acc.y + acc.z + acc.w;
  }
  __syncthreads();

  if (tid < NCLS) {
    const float4* wrow = (const float4*)(Wd + (long)tid * DD);
    const float4* dv4 = (const float4*)dvec;
    float4 acc = {0.f, 0.f, 0.f, 0.f};
    for (int iq = 0; iq < 128; ++iq) {
      float4 w = wrow[iq]; float4 d = dv4[iq];
      acc.x += w.x*d.x; acc.y += w.y*d.y; acc.z += w.z*d.z; acc.w += w.w*d.w;
    }
    out[b * NCLS + tid] = bd[tid] + acc.x + acc.y + acc.z + acc.w;
  }
}

extern "C" void kernel_launch(void* const* d_in, const int* in_sizes, int n_in,
                              void* d_out, int out_size, void* d_ws, size_t ws_size,
                              hipStream_t stream)
{
  const int*   x    = (const int*)  d_in[0];
  const int*   eos  = (const int*)  d_in[1];
  const float* emb  = (const float*)d_in[2];
  const float* W_ih = (const float*)d_in[3];
  const float* W_hh = (const float*)d_in[4];
  const float* b_ih = (const float*)d_in[5];
  const float* b_hh = (const float*)d_in[6];
  const float* Wc   = (const float*)d_in[7];
  const float* bc   = (const float*)d_in[8];
  const float* Wd   = (const float*)d_in[9];
  const float* bd   = (const float*)d_in[10];
  float* out = (float*)d_out;

  // workspace: Abuf (h2+2) | Bbuf (xproj->h1+2). Poison 0xAA = -3e-13 < 1 => "not ready".
  float* Abuf = (float*)d_ws;
  float* Bbuf = Abuf + (size_t)NB * LL * DD;

  k_gemm_embed<<<2048, 256, 0, stream>>>(x, emb, W_ih, b_ih, b_hh, Bbuf);
  k_scan<<<512, 256, 0, stream>>>(W_ih, W_hh, b_ih, b_hh, Bbuf, Abuf);
  k_attn<<<NB, 256, 0, stream>>>(Abuf, eos, Wc, bc, Wd, bd, out);
}

// Round 6
// 2026.945 us; speedup vs baseline: 1.3892x; 1.0771x over previous
//
#include <hip/hip_runtime.h>
#include <cmath>

#define NB   16
#define LL   1024
#define DD   512
#define NCLS 64

// ---------------------------------------------- fused embed-gather + proj GEMM
// C[m][n] = b1[n] + b2[n] + sum_k emb[x[m]][k] * W[n][k]   (M=16384, N=K=512)
__global__ __launch_bounds__(256) void k_gemm_embed(
    const int* __restrict__ x, const float* __restrict__ emb,
    const float* __restrict__ W, const float* __restrict__ b1,
    const float* __restrict__ b2, float* __restrict__ C)
{
  __shared__ __align__(16) float As[32][68];  // [k][m], +4 pad
  __shared__ __align__(16) float Ws[32][68];  // [k][n]
  const int tid = threadIdx.x;
  const int n0 = (blockIdx.x & 7) * 64;
  const int m0 = (blockIdx.x >> 3) * 64;
  const int tm = tid & 15, tn = tid >> 4;
  float acc[4][4] = {};

  const int f0 = tid * 2, f1 = tid * 2 + 1;
  const int r0 = f0 >> 3, q0 = f0 & 7;
  const int r1 = f1 >> 3, q1 = f1 & 7;
  const long arow0 = (long)x[m0 + r0] * DD;
  const long arow1 = (long)x[m0 + r1] * DD;
  const long wrow0 = (long)(n0 + r0) * DD;
  const long wrow1 = (long)(n0 + r1) * DD;

  for (int k0 = 0; k0 < DD; k0 += 32) {
    float4 va = *(const float4*)(emb + arow0 + k0 + q0 * 4);
    float4 vb = *(const float4*)(emb + arow1 + k0 + q1 * 4);
    float4 wa = *(const float4*)(W + wrow0 + k0 + q0 * 4);
    float4 wb = *(const float4*)(W + wrow1 + k0 + q1 * 4);
    __syncthreads();
    As[q0*4+0][r0]=va.x; As[q0*4+1][r0]=va.y; As[q0*4+2][r0]=va.z; As[q0*4+3][r0]=va.w;
    As[q1*4+0][r1]=vb.x; As[q1*4+1][r1]=vb.y; As[q1*4+2][r1]=vb.z; As[q1*4+3][r1]=vb.w;
    Ws[q0*4+0][r0]=wa.x; Ws[q0*4+1][r0]=wa.y; Ws[q0*4+2][r0]=wa.z; Ws[q0*4+3][r0]=wa.w;
    Ws[q1*4+0][r1]=wb.x; Ws[q1*4+1][r1]=wb.y; Ws[q1*4+2][r1]=wb.z; Ws[q1*4+3][r1]=wb.w;
    __syncthreads();
    #pragma unroll
    for (int kk = 0; kk < 32; ++kk) {
      float4 a = *(const float4*)&As[kk][tm * 4];
      float4 w = *(const float4*)&Ws[kk][tn * 4];
      acc[0][0]+=a.x*w.x; acc[0][1]+=a.x*w.y; acc[0][2]+=a.x*w.z; acc[0][3]+=a.x*w.w;
      acc[1][0]+=a.y*w.x; acc[1][1]+=a.y*w.y; acc[1][2]+=a.y*w.z; acc[1][3]+=a.y*w.w;
      acc[2][0]+=a.z*w.x; acc[2][1]+=a.z*w.y; acc[2][2]+=a.z*w.z; acc[2][3]+=a.z*w.w;
      acc[3][0]+=a.w*w.x; acc[3][1]+=a.w*w.y; acc[3][2]+=a.w*w.z; acc[3][3]+=a.w*w.w;
    }
  }
  float bj[4];
  #pragma unroll
  for (int j = 0; j < 4; ++j)
    bj[j] = b1[n0 + tn * 4 + j] + b2[n0 + tn * 4 + j];
  #pragma unroll
  for (int i = 0; i < 4; ++i) {
    const int m = m0 + tm * 4 + i;
    float4 o = { acc[i][0]+bj[0], acc[i][1]+bj[1], acc[i][2]+bj[2], acc[i][3]+bj[3] };
    *(float4*)(C + (long)m * DD + n0 + tn * 4) = o;
  }
}

// ---------------------------------------------------------------- scan helpers
// 8-lane-group sum via DPP (VALU cross-lane) instead of ds_swizzle (LDS pipe).
template<int CTRL>
__device__ __forceinline__ float dpp_add(float x) {
  int s = __builtin_amdgcn_update_dpp(0, __float_as_int(x), CTRL, 0xF, 0xF, true);
  return x + __int_as_float(s);
}
__device__ __forceinline__ float wave_red8(float y) {
  y = dpp_add<0xB1>(y);    // quad_perm xor1
  y = dpp_add<0x4E>(y);    // quad_perm xor2
  y = dpp_add<0x141>(y);   // row_half_mirror (other quad of the 8-group)
  return y;
}

// fast tanh via v_exp_f32 + v_rcp_f32; |err|~1e-7, recurrence contractive.
__device__ __forceinline__ float fast_tanh(float x) {
  float e = __expf(2.0f * x);
  return 1.0f - __fdividef(2.0f, 1.0f + e);
}

__device__ __forceinline__ float poll_ld(const float* p) {
  return __hip_atomic_load(p, __ATOMIC_RELAXED, __HIP_MEMORY_SCOPE_AGENT);
}
__device__ __forceinline__ void enc_st(float* p, float v) {
  __hip_atomic_store(p, v + 2.0f, __ATOMIC_RELAXED, __HIP_MEMORY_SCOPE_AGENT);
}
// drain the handshake store to L2 before flooding the pipe with polls
__device__ __forceinline__ void st_drain() {
  asm volatile("s_waitcnt vmcnt(0)" ::: "memory");
}
// 64-MAC dot with 4 independent accumulation chains (float4 components).
__device__ __forceinline__ void dot64(const float* w, const float4* h4, float4& a) {
  #pragma unroll
  for (int q = 0; q < 16; ++q) {
    float4 h = h4[q];
    a.x += w[4*q+0]*h.x; a.y += w[4*q+1]*h.y;
    a.z += w[4*q+2]*h.z; a.w += w[4*q+3]*h.w;
  }
}
__device__ __forceinline__ float hsum4(const float4& a) { return (a.x+a.y)+(a.z+a.w); }

// ------------------------------------------------- persistent 2-layer RNN scan
// ROUND-5 VERIFIED STRUCTURE (2183us) + poll backoff (s_sleep) + store drains.
// Theory: the 512-WG value-spin saturates each XCD L2 (~3.4 line-req/cy),
// queueing every handshake store/load behind spin traffic. s_sleep(2) halves
// the spin request rate (first check is sleep-free); vmcnt(0) after each
// handshake store drains it before the wave re-enters its poll flood.
__global__ __launch_bounds__(256, 2) void k_scan(
    const float* __restrict__ W_ih, const float* __restrict__ W_hh,
    const float* __restrict__ b_ih, const float* __restrict__ b_hh,
    float* __restrict__ Bbuf,   // in: xproj layer1 -> h1+2 (in-place, encoded)
    float* __restrict__ Abuf)   // h2+2 (O2, encoded)
{
  const int g = blockIdx.x;
  const int lay = g >> 8;          // 0: h1 chain, 1: h2 chain
  const int b = g & 15;            // batch
  const int j = (g & 255) >> 4;    // WG index within (layer,batch) [0,16)
  const int tid = threadIdx.x;
  const int part = tid & 7;        // k-part [0,8), 64 elems each
  const int rl  = tid >> 3;        // row_local [0,32)
  const int row = j * 32 + rl;     // global hidden row
  const bool leader = (part == 0);

  __shared__ __align__(16) float hS[2][8 * 68];  // recurrence-state stage, dbuf
  __shared__ __align__(16) float hT[2][8 * 68];  // h1 stage for layer-2's M2

  float* Bb = Bbuf + (long)b * LL * DD;
  float* Ab = Abuf + (long)b * LL * DD;

  const int i0 = tid, i1 = tid + 256;
  const int d0 = (i0 >> 6) * 68 + (i0 & 63);
  const int d1 = (i1 >> 6) * 68 + (i1 & 63);

  if (lay == 0) {
    // ------------ layer 1: h1(t) = tanh(xproj(t) + Whh1 . h1(t-1)) ----------
    float w1[64];
    {
      const float* p1 = W_hh + (long)row * DD + part * 64;
      #pragma unroll
      for (int q = 0; q < 64; ++q) w1[q] = p1[q];
    }
    #pragma unroll
    for (int q = 0; q < 64; ++q) asm volatile("" : "+v"(w1[q]));  // pin in VGPRs

    float xpv = 0.f, xnext = 0.f;
    if (leader) {
      xpv   = Bb[row];            // xproj(0)  (gemm completed: plain loads ok)
      xnext = Bb[DD + row];       // prefetch xproj(1) a full step ahead
      enc_st(Bb + row, fast_tanh(xpv));   // h1(0)
    }
    st_drain();
    for (int t = 1; t < LL; ++t) {
      const int bufi = t & 1;
      xpv = xnext;
      if (leader && (t + 1 < LL)) xnext = Bb[(long)(t + 1) * DD + row];
      // poll h1(t-1) — sleep-free first check, then backoff spin
      const float* s1 = Bb + (long)(t - 1) * DD;
      float v0 = poll_ld(s1 + i0), v1 = poll_ld(s1 + i1);
      while (fminf(v0, v1) <= 1.0f) {
        __builtin_amdgcn_s_sleep(2);
        v0 = poll_ld(s1 + i0); v1 = poll_ld(s1 + i1);
      }
      hS[bufi][d0] = v0 - 2.0f; hS[bufi][d1] = v1 - 2.0f;
      __syncthreads();
      float4 a = {0.f, 0.f, 0.f, 0.f};
      dot64(w1, (const float4*)&hS[bufi][part * 68], a);
      float y = wave_red8(hsum4(a));
      if (leader) enc_st(Bb + (long)t * DD + row, fast_tanh(xpv + y));
      st_drain();
    }
  } else {
    // ------ layer 2: h2(t) = tanh(Wih2.h1(t) + bias2 + Whh2.h2(t-1)) --------
    float w2[64], w3[64];
    {
      const float* p2 = W_ih + (long)DD * DD + (long)row * DD + part * 64;
      const float* p3 = W_hh + (long)DD * DD + (long)row * DD + part * 64;
      #pragma unroll
      for (int q = 0; q < 64; ++q) { w2[q] = p2[q]; w3[q] = p3[q]; }
    }
    #pragma unroll
    for (int q = 0; q < 64; ++q) {
      asm volatile("" : "+v"(w2[q]));
      asm volatile("" : "+v"(w3[q]));
    }
    const float bias2 = b_ih[DD + row] + b_hh[DD + row];

    // prologue: xin2(0) = Wih2 . h1(0) + bias2
    float xin2;
    {
      const float* s1 = Bb;   // h1(0), encoded (xproj < 1 until overwritten)
      float v0 = poll_ld(s1 + i0), v1 = poll_ld(s1 + i1);
      while (fminf(v0, v1) <= 1.0f) {
        __builtin_amdgcn_s_sleep(2);
        v0 = poll_ld(s1 + i0); v1 = poll_ld(s1 + i1);
      }
      hT[1][d0] = v0 - 2.0f; hT[1][d1] = v1 - 2.0f;
      __syncthreads();
      float4 a = {0.f, 0.f, 0.f, 0.f};
      dot64(w2, (const float4*)&hT[1][part * 68], a);
      xin2 = wave_red8(hsum4(a)) + bias2;
    }
    // iter t: store h2(t) (using xin2(t)), then compute xin2(t+1) from h1(t+1)
    // — M2 sits between the h2 store and the next poll, hiding store->poll.
    for (int t = 0; t < LL; ++t) {
      const int bufi = t & 1;
      const bool st2 = (t >= 1);        // h2(t-1) exists
      const bool st1 = (t + 1 < LL);    // need h1(t+1)
      {
        const float* s2 = Ab + (long)(t - 1) * DD;
        const float* s1 = Bb + (long)(t + 1) * DD;
        float u0 = 3.f, u1 = 3.f, v0 = 3.f, v1 = 3.f;
        if (st2) { u0 = poll_ld(s2 + i0); u1 = poll_ld(s2 + i1); }
        if (st1) { v0 = poll_ld(s1 + i0); v1 = poll_ld(s1 + i1); }
        while (fminf(fminf(u0, u1), fminf(v0, v1)) <= 1.0f) {
          __builtin_amdgcn_s_sleep(2);
          if (st2) { u0 = poll_ld(s2 + i0); u1 = poll_ld(s2 + i1); }
          if (st1) { v0 = poll_ld(s1 + i0); v1 = poll_ld(s1 + i1); }
        }
        if (st2) { hS[bufi][d0] = u0 - 2.0f; hS[bufi][d1] = u1 - 2.0f; }
        if (st1) { hT[bufi][d0] = v0 - 2.0f; hT[bufi][d1] = v1 - 2.0f; }
      }
      __syncthreads();
      // M3: h2(t) = tanh(xin2(t) + Whh2 . h2(t-1))
      float y3 = 0.f;
      if (st2) {
        float4 a = {0.f, 0.f, 0.f, 0.f};
        dot64(w3, (const float4*)&hS[bufi][part * 68], a);
        y3 = hsum4(a);
      }
      y3 = wave_red8(y3);
      if (leader) enc_st(Ab + (long)t * DD + row, fast_tanh(xin2 + y3));
      st_drain();
      // M2: xin2(t+1) = Wih2 . h1(t+1) + bias2 (off the h2 critical hop)
      if (st1) {
        float4 a = {0.f, 0.f, 0.f, 0.f};
        dot64(w2, (const float4*)&hT[bufi][part * 68], a);
        xin2 = wave_red8(hsum4(a)) + bias2;
      }
    }
  }
}

// ------------------------------------------- attention row @ eos + decode head
// O2 is stored ENCODED (h+2). Decode: q explicitly; scores via qsum trick;
// att_z via sum(p)=1 -> subtract 2 at the end.
__global__ __launch_bounds__(256) void k_attn(
    const float* __restrict__ O2, const int* __restrict__ eos,
    const float* __restrict__ Wc, const float* __restrict__ bc,
    const float* __restrict__ Wd, const float* __restrict__ bd,
    float* __restrict__ out)
{
  const int b = blockIdx.x;
  const int tid = threadIdx.x;
  const int te = eos[b];
  __shared__ __align__(16) float q[DD];
  __shared__ float ps[LL];
  __shared__ float red[256];
  __shared__ __align__(16) float din[2 * DD];
  __shared__ __align__(16) float dvec[DD];
  const float* Ob = O2 + (long)b * LL * DD;
  const float4* Ob4 = (const float4*)Ob;

  float qpart = 0.f;
  for (int i = tid; i < DD; i += 256) {
    float v = Ob[(long)te * DD + i] - 2.0f;   // decode
    q[i] = v; qpart += v;
  }
  red[tid] = qpart; __syncthreads();
  for (int off = 128; off > 0; off >>= 1) {
    if (tid < off) red[tid] += red[tid + off];
    __syncthreads();
  }
  const float qsum = red[0];
  __syncthreads();
  const float4* q4 = (const float4*)q;

  // masked scores: raw dot(o_enc, q) - 2*qsum == dot(o, q)
  for (int ss = tid; ss < LL; ss += 256) {
    float sc = -1.0e9f;
    if (ss < te) {
      float4 acc = {0.f, 0.f, 0.f, 0.f};
      for (int kq = 0; kq < 128; ++kq) {
        float4 o = Ob4[ss * 128 + kq];
        float4 qq = q4[kq];
        acc.x += o.x*qq.x; acc.y += o.y*qq.y; acc.z += o.z*qq.z; acc.w += o.w*qq.w;
      }
      sc = acc.x + acc.y + acc.z + acc.w - 2.0f * qsum;
    }
    ps[ss] = sc;
  }
  __syncthreads();
  float m = -3.0e38f;
  for (int ss = tid; ss < LL; ss += 256) m = fmaxf(m, ps[ss]);
  red[tid] = m; __syncthreads();
  for (int off = 128; off > 0; off >>= 1) {
    if (tid < off) red[tid] = fmaxf(red[tid], red[tid + off]);
    __syncthreads();
  }
  m = red[0]; __syncthreads();
  float lsum = 0.f;
  for (int ss = tid; ss < LL; ss += 256) {
    float e = expf(ps[ss] - m);
    ps[ss] = e; lsum += e;
  }
  __syncthreads();
  red[tid] = lsum; __syncthreads();
  for (int off = 128; off > 0; off >>= 1) {
    if (tid < off) red[tid] += red[tid + off];
    __syncthreads();
  }
  const float inv = 1.0f / red[0];
  __syncthreads();
  for (int ss = tid; ss < LL; ss += 256) ps[ss] *= inv;
  __syncthreads();

  // att_z (encoded: sum p*o_enc - 2 since sum p = 1), z-copy (already decoded)
  if (tid < 128) {
    float4 acc = {0.f, 0.f, 0.f, 0.f};
    for (int ss = 0; ss < LL; ++ss) {
      float p = ps[ss];
      if (p != 0.0f) {
        float4 o = Ob4[ss * 128 + tid];
        acc.x += p*o.x; acc.y += p*o.y; acc.z += p*o.z; acc.w += p*o.w;
      }
    }
    acc.x -= 2.0f; acc.y -= 2.0f; acc.z -= 2.0f; acc.w -= 2.0f;
    ((float4*)din)[tid] = acc;
  } else {
    const int c = tid - 128;
    ((float4*)din)[128 + c] = q4[c];
  }
  __syncthreads();

  const float4* din4 = (const float4*)din;
  for (int jj = tid; jj < DD; jj += 256) {
    const float4* wrow = (const float4*)(Wc + (long)jj * 2 * DD);
    float4 acc = {0.f, 0.f, 0.f, 0.f};
    for (int iq = 0; iq < 256; ++iq) {
      float4 w = wrow[iq]; float4 d = din4[iq];
      acc.x += w.x*d.x; acc.y += w.y*d.y; acc.z += w.z*d.z; acc.w += w.w*d.w;
    }
    dvec[jj] = bc[jj] + acc.x + acc.y + acc.z + acc.w;
  }
  __syncthreads();

  if (tid < NCLS) {
    const float4* wrow = (const float4*)(Wd + (long)tid * DD);
    const float4* dv4 = (const float4*)dvec;
    float4 acc = {0.f, 0.f, 0.f, 0.f};
    for (int iq = 0; iq < 128; ++iq) {
      float4 w = wrow[iq]; float4 d = dv4[iq];
      acc.x += w.x*d.x; acc.y += w.y*d.y; acc.z += w.z*d.z; acc.w += w.w*d.w;
    }
    out[b * NCLS + tid] = bd[tid] + acc.x + acc.y + acc.z + acc.w;
  }
}

extern "C" void kernel_launch(void* const* d_in, const int* in_sizes, int n_in,
                              void* d_out, int out_size, void* d_ws, size_t ws_size,
                              hipStream_t stream)
{
  const int*   x    = (const int*)  d_in[0];
  const int*   eos  = (const int*)  d_in[1];
  const float* emb  = (const float*)d_in[2];
  const float* W_ih = (const float*)d_in[3];
  const float* W_hh = (const float*)d_in[4];
  const float* b_ih = (const float*)d_in[5];
  const float* b_hh = (const float*)d_in[6];
  const float* Wc   = (const float*)d_in[7];
  const float* bc   = (const float*)d_in[8];
  const float* Wd   = (const float*)d_in[9];
  const float* bd   = (const float*)d_in[10];
  float* out = (float*)d_out;

  // workspace: Abuf (h2+2) | Bbuf (xproj->h1+2). Poison 0xAA = -3e-13 < 1 => "not ready".
  float* Abuf = (float*)d_ws;
  float* Bbuf = Abuf + (size_t)NB * LL * DD;

  k_gemm_embed<<<2048, 256, 0, stream>>>(x, emb, W_ih, b_ih, b_hh, Bbuf);
  k_scan<<<512, 256, 0, stream>>>(W_ih, W_hh, b_ih, b_hh, Bbuf, Abuf);
  k_attn<<<NB, 256, 0, stream>>>(Abuf, eos, Wc, bc, Wd, bd, out);
}